// Round 5
// baseline (1089.550 us; speedup 1.0000x reference)
//
#include <hip/hip_runtime.h>

typedef unsigned short u16;
typedef unsigned int u32;

typedef short bf16x8 __attribute__((ext_vector_type(8)));
typedef float f32x4 __attribute__((ext_vector_type(4)));
typedef float f32x16 __attribute__((ext_vector_type(16)));

#define T_SEQ 2048
#define MFMA16(a, b, c) __builtin_amdgcn_mfma_f32_16x16x32_bf16(a, b, c, 0, 0, 0)
#define MFMA32(a, b, c) __builtin_amdgcn_mfma_f32_32x32x16_bf16(a, b, c, 0, 0, 0)

__device__ __forceinline__ u16 f2bf(float f) {
    u32 u = __float_as_uint(f);
    u += 0x7fffu + ((u >> 16) & 1u);
    return (u16)(u >> 16);
}
__device__ __forceinline__ float bf2f(u16 s) {
    return __uint_as_float(((u32)s) << 16);
}
__device__ __forceinline__ void g2lds16(const u16* gp, u16* lp) {
    __builtin_amdgcn_global_load_lds((const __attribute__((address_space(1))) void*)gp,
                                     (__attribute__((address_space(3))) void*)lp, 16, 0, 0);
}

// ---------------- cast fp32 -> bf16 ----------------
__global__ __launch_bounds__(256) void cast_f32_bf16(const float* __restrict__ in,
                                                     u16* __restrict__ out, long n) {
    long i = ((long)blockIdx.x * 256 + threadIdx.x) * 4;
    if (i + 3 < n) {
        float4 v = *(const float4*)&in[i];
        out[i + 0] = f2bf(v.x);
        out[i + 1] = f2bf(v.y);
        out[i + 2] = f2bf(v.z);
        out[i + 3] = f2bf(v.w);
    }
}

// ---------------- transpose + cast: [R,C] f32 -> [C,R] bf16 ----------------
__global__ __launch_bounds__(256) void transpose_cast(const float* __restrict__ in,
                                                      u16* __restrict__ out, int R, int C) {
    __shared__ float tile[32][33];
    int c0 = blockIdx.x * 32, r0 = blockIdx.y * 32;
    int tx = threadIdx.x & 31, ty = threadIdx.x >> 5;
#pragma unroll
    for (int rr = 0; rr < 32; rr += 8)
        tile[ty + rr][tx] = in[(long)(r0 + ty + rr) * C + c0 + tx];
    __syncthreads();
#pragma unroll
    for (int rr = 0; rr < 32; rr += 8)
        out[(long)(c0 + ty + rr) * R + r0 + tx] = f2bf(tile[tx][ty + rr]);
}

// ---------------- GEMM: C[M,N] = A[M,K] * BT[N,K], 32x32x16 MFMA, XOR-swizzled LDS --------
// MODE 0: f32 out ; MODE 2: split bf16 qkv(cols<8192, ld 8192)/z(ld 4096)
template <int MODE>
__global__ __launch_bounds__(256) void gemm_bt(const u16* __restrict__ A,
                                               const u16* __restrict__ B, void* __restrict__ C,
                                               void* __restrict__ C2, int M, int N, int K, int lda,
                                               int ldb, int ldc) {
    __shared__ __align__(16) u16 As[128 * 32];
    __shared__ __align__(16) u16 Bs[128 * 32];
    int m0 = blockIdx.x * 128, n0 = blockIdx.y * 128;
    int tid = threadIdx.x;
    int lane = tid & 63, w = tid >> 6;
    int wr = w >> 1, wc = w & 1;
    int l31 = lane & 31, hf = lane >> 5;
    int swz = (l31 >> 1) & 3;  // fragment-read cell swizzle

    f32x16 acc[2][2];
#pragma unroll
    for (int mi = 0; mi < 2; mi++)
#pragma unroll
        for (int nj = 0; nj < 2; nj++)
#pragma unroll
            for (int r = 0; r < 16; r++) acc[mi][nj][r] = 0.f;

    // staging: LDS cell (row, tid&3) holds global column-group (tid&3)^((srow>>1)&3)
    int srow = tid >> 2;
    int sc8 = (((tid & 3) ^ ((srow >> 1) & 3))) * 8;
    const u16* Ag = &A[(long)(m0 + srow) * lda + sc8];
    const u16* Bg = &B[(long)(n0 + srow) * ldb + sc8];

    for (int k0 = 0; k0 < K; k0 += 32) {
        g2lds16(Ag + k0, &As[tid * 8]);
        g2lds16(Ag + (long)64 * lda + k0, &As[(256 + tid) * 8]);
        g2lds16(Bg + k0, &Bs[tid * 8]);
        g2lds16(Bg + (long)64 * ldb + k0, &Bs[(256 + tid) * 8]);
        __syncthreads();
        bf16x8 af[2][2], bfr[2][2];
#pragma unroll
        for (int mi = 0; mi < 2; mi++)
#pragma unroll
            for (int ks = 0; ks < 2; ks++) {
                int cellA = ((ks * 2 + hf) ^ swz) * 8;
                af[mi][ks] = *(const bf16x8*)&As[(wr * 64 + mi * 32 + l31) * 32 + cellA];
                bfr[mi][ks] = *(const bf16x8*)&Bs[(wc * 64 + mi * 32 + l31) * 32 + cellA];
            }
#pragma unroll
        for (int ks = 0; ks < 2; ks++)
#pragma unroll
            for (int mi = 0; mi < 2; mi++)
#pragma unroll
                for (int nj = 0; nj < 2; nj++)
                    acc[mi][nj] = MFMA32(af[mi][ks], bfr[nj][ks], acc[mi][nj]);
        __syncthreads();
    }

    if (MODE == 0) {
#pragma unroll
        for (int mi = 0; mi < 2; mi++)
#pragma unroll
            for (int nj = 0; nj < 2; nj++)
#pragma unroll
                for (int r = 0; r < 16; r++) {
                    int row = m0 + wr * 64 + mi * 32 + (r >> 2) * 8 + hf * 4 + (r & 3);
                    int col = n0 + wc * 64 + nj * 32 + l31;
                    ((float*)C)[(long)row * ldc + col] = acc[mi][nj][r];
                }
    } else {
        u16* dst;
        long dldc;
        int ncol0;
        if (MODE == 2 && n0 >= 8192) {
            dst = (u16*)C2;
            dldc = 4096;
            ncol0 = n0 - 8192;
        } else {
            dst = (u16*)C;
            dldc = (MODE == 2) ? 8192 : ldc;
            ncol0 = n0;
        }
#pragma unroll 1
        for (int half_e = 0; half_e < 2; half_e++) {
            __syncthreads();
            if (wc == half_e) {
#pragma unroll
                for (int mi = 0; mi < 2; mi++)
#pragma unroll
                    for (int nj = 0; nj < 2; nj++)
#pragma unroll
                        for (int r = 0; r < 16; r++) {
                            int row = wr * 64 + mi * 32 + (r >> 2) * 8 + hf * 4 + (r & 3);
                            int col = nj * 32 + l31;
                            u16* base = (row < 64) ? As : Bs;
                            base[(row & 63) * 64 + col] = f2bf(acc[mi][nj][r]);
                        }
            }
            __syncthreads();
#pragma unroll
            for (int rr = 0; rr < 4; rr++) {
                int row = rr * 32 + (tid >> 3), seg = tid & 7;
                u16* base = (row < 64) ? As : Bs;
                *(uint4*)&dst[(long)(m0 + row) * dldc + ncol0 + half_e * 64 + seg * 8] =
                    *(uint4*)&base[(row & 63) * 64 + seg * 8];
            }
        }
    }
}

// ---------------- ba = hidden @ W_ba -> g, beta (MFMA, padded LDS) ----------------
__global__ __launch_bounds__(256) void ba_gemm(const u16* __restrict__ hid,
                                               const u16* __restrict__ WbaT,
                                               const float* __restrict__ A_log,
                                               const float* __restrict__ dt_bias,
                                               float* __restrict__ g, float* __restrict__ beta) {
    __shared__ __align__(16) u16 As2[32 * 40];
    __shared__ __align__(16) u16 Bs2[64 * 40];
    int m0 = blockIdx.x * 32;
    int tid = threadIdx.x, lane = tid & 63, w = tid >> 6;
    int quad = lane >> 4, l15 = lane & 15;
    int trow = w & 1;
    int ctile = (w >> 1) * 2;
    f32x4 acc[2];
    acc[0] = (f32x4){0.f, 0.f, 0.f, 0.f};
    acc[1] = (f32x4){0.f, 0.f, 0.f, 0.f};
    int srow = tid >> 2, sc8 = (tid & 3) * 8;
    for (int k0 = 0; k0 < 2048; k0 += 32) {
        if (tid < 128)
            *(uint4*)&As2[srow * 40 + sc8] =
                *(const uint4*)&hid[(long)(m0 + srow) * 2048 + k0 + sc8];
        *(uint4*)&Bs2[srow * 40 + sc8] = *(const uint4*)&WbaT[(long)srow * 2048 + k0 + sc8];
        __syncthreads();
        bf16x8 a = *(const bf16x8*)&As2[(trow * 16 + l15) * 40 + quad * 8];
#pragma unroll
        for (int j = 0; j < 2; j++) {
            bf16x8 b = *(const bf16x8*)&Bs2[((ctile + j) * 16 + l15) * 40 + quad * 8];
            acc[j] = MFMA16(a, b, acc[j]);
        }
        __syncthreads();
    }
#pragma unroll
    for (int j = 0; j < 2; j++)
#pragma unroll
        for (int r = 0; r < 4; r++) {
            int tok = m0 + trow * 16 + quad * 4 + r;
            int col = (ctile + j) * 16 + l15;
            float tot = acc[j][r];
            if (col < 32) {
                beta[(long)tok * 32 + col] = 1.f / (1.f + expf(-tot));
            } else {
                int h = col - 32;
                float x = tot + dt_bias[h];
                float sp = (x > 20.f) ? x : log1pf(expf(x));
                g[(long)tok * 32 + h] = -expf(A_log[h]) * sp;
            }
        }
}

// ---------------- causal conv + SiLU + l2norm + split (register-only) ----------------
__global__ __launch_bounds__(256) void conv_gate(const u16* __restrict__ qkv,
                                                 const float* __restrict__ conv_w,
                                                 u16* __restrict__ qn, u16* __restrict__ kn,
                                                 u16* __restrict__ vc) {
    int tok = blockIdx.x, tid = threadIdx.x;
    int tloc = tok & (T_SEQ - 1);
    int c0 = tid * 32;  // 32 consecutive channels per thread (one norm-group = 4 threads)
    long base = (long)tok * 8192 + c0;
    float mx[32];
    uint4 zero4;
    zero4.x = zero4.y = zero4.z = zero4.w = 0u;
#pragma unroll
    for (int e8 = 0; e8 < 4; e8++) {
        long b8 = base + e8 * 8;
        uint4 x3 = *(const uint4*)&qkv[b8];
        uint4 x2 = (tloc >= 1) ? *(const uint4*)&qkv[b8 - 8192] : zero4;
        uint4 x1 = (tloc >= 2) ? *(const uint4*)&qkv[b8 - 16384] : zero4;
        uint4 x0 = (tloc >= 3) ? *(const uint4*)&qkv[b8 - 24576] : zero4;
        const u16* p0 = (const u16*)&x0;
        const u16* p1 = (const u16*)&x1;
        const u16* p2 = (const u16*)&x2;
        const u16* p3 = (const u16*)&x3;
#pragma unroll
        for (int e = 0; e < 8; e++) {
            float4 wv = *(const float4*)&conv_w[(long)(c0 + e8 * 8 + e) * 4];
            float a = bf2f(p0[e]) * wv.x + bf2f(p1[e]) * wv.y + bf2f(p2[e]) * wv.z +
                      bf2f(p3[e]) * wv.w;
            mx[e8 * 8 + e] = a / (1.f + __expf(-a));
        }
    }
    float nf = 1.f;
    if (c0 < 4096) {
        float ss = 0.f;
#pragma unroll
        for (int e = 0; e < 32; e++) ss += mx[e] * mx[e];
        ss += __shfl_xor(ss, 1, 4);
        ss += __shfl_xor(ss, 2, 4);
        nf = rsqrtf(ss + 1e-6f);
        if (c0 < 2048) nf *= 0.08838834764831845f;
    }
#pragma unroll
    for (int e8 = 0; e8 < 4; e8++) {
        u16 ob[8];
#pragma unroll
        for (int e = 0; e < 8; e++) ob[e] = f2bf(mx[e8 * 8 + e] * nf);
        uint4 val = *(uint4*)ob;
        int c = c0 + e8 * 8;
        if (c0 < 2048)
            *(uint4*)&qn[(long)tok * 2048 + c] = val;
        else if (c0 < 4096)
            *(uint4*)&kn[(long)tok * 2048 + (c - 2048)] = val;
        else
            *(uint4*)&vc[(long)tok * 4096 + (c - 4096)] = val;
    }
}

// ---------------- phase A: per-chunk WY transform (padded LDS, YT transposed) ----------
__global__ __launch_bounds__(256) void phaseA(const u16* __restrict__ qn,
                                              const u16* __restrict__ kn,
                                              const u16* __restrict__ vc,
                                              const float* __restrict__ g,
                                              const float* __restrict__ beta,
                                              u16* __restrict__ Tv_g, u16* __restrict__ Tw_g,
                                              u16* __restrict__ Q2_g, u16* __restrict__ obuf) {
    __shared__ __align__(16) u16 kbuf[64][136];  // k tile (padded); later L at stride 72
    __shared__ __align__(16) float BMt[64][68];  // BMt[j][i] (padded)
    __shared__ __align__(16) u16 YT[256][72];    // Y^T: row=col(0..127 V / 128..255 W), col=token
    u16* Lbf = &kbuf[0][0];

    int bid = blockIdx.x;
    int c = bid & 31, h = (bid >> 5) & 31, b = bid >> 10;
    int hk = h >> 1;
    long tokbase = (long)b * T_SEQ + c * 64;
    long cb = (long)bid * 8192;
    int tid = threadIdx.x, lane = tid & 63, w = tid >> 6;
    int quad = lane >> 4, l15 = lane & 15;

    float gl = g[(tokbase + lane) * 32 + h];
    float bl = beta[(tokbase + lane) * 32 + h];
    float cgl = gl;
#pragma unroll
    for (int d = 1; d < 64; d <<= 1) {
        float y = __shfl_up(cgl, d);
        if (lane >= d) cgl += y;
    }
    float wscl = bl * __expf(cgl);
    float eCgl = __expf(cgl);

#pragma unroll
    for (int p = 0; p < 4; p++) {
        int u = p * 256 + tid;
        int row = u >> 4, col8 = (u & 15) * 8;
        *(uint4*)&kbuf[row][col8] = *(const uint4*)&kn[(tokbase + row) * 2048 + hk * 128 + col8];
    }
    __syncthreads();

    // Gram_kk -> BMt
    {
        f32x4 gk[4];
#pragma unroll
        for (int nj = 0; nj < 4; nj++) gk[nj] = (f32x4){0.f, 0.f, 0.f, 0.f};
#pragma unroll
        for (int kk = 0; kk < 4; kk++) {
            bf16x8 a = *(const bf16x8*)&kbuf[w * 16 + l15][kk * 32 + quad * 8];
#pragma unroll
            for (int nj = 0; nj < 4; nj++) {
                bf16x8 bb = *(const bf16x8*)&kbuf[nj * 16 + l15][kk * 32 + quad * 8];
                gk[nj] = MFMA16(a, bb, gk[nj]);
            }
        }
#pragma unroll
        for (int nj = 0; nj < 4; nj++)
#pragma unroll
            for (int r = 0; r < 4; r++) {
                int i = w * 16 + quad * 4 + r;
                int j = nj * 16 + l15;
                float cgi = __shfl(cgl, i), cgj = __shfl(cgl, j);
                float bi = __shfl(bl, i);
                BMt[j][i] = (j < i) ? bi * gk[nj][r] * __expf(cgi - cgj) : 0.f;
            }
    }
    __syncthreads();

    // blocked forward substitution: (I+BM) Y = B*[V | W] ; Y^T into YT
    {
        int col = tid;
        bool isV = col < 128;
        int kcol = col & 127;
        long vbase = tokbase * 4096 + h * 128 + kcol;
        float Yreg[8], acc8[8];
#pragma unroll 1
        for (int bi = 0; bi < 8; ++bi) {
            float vr[8];
            if (isV) {
#pragma unroll
                for (int ii = 0; ii < 8; ii++)
                    vr[ii] = bf2f(vc[vbase + (long)(bi * 8 + ii) * 4096]);
            }
#pragma unroll
            for (int ii = 0; ii < 8; ii++) acc8[ii] = 0.f;
            for (int j = 0; j < bi * 8; ++j) {
                float yv = bf2f(YT[col][j]);
                float4 m0 = *(const float4*)&BMt[j][bi * 8];
                float4 m1 = *(const float4*)&BMt[j][bi * 8 + 4];
                acc8[0] += m0.x * yv;
                acc8[1] += m0.y * yv;
                acc8[2] += m0.z * yv;
                acc8[3] += m0.w * yv;
                acc8[4] += m1.x * yv;
                acc8[5] += m1.y * yv;
                acc8[6] += m1.z * yv;
                acc8[7] += m1.w * yv;
            }
            u16 outb[8];
#pragma unroll
            for (int ii = 0; ii < 8; ii++) {
                int i = bi * 8 + ii;
                float rhs = isV ? __shfl(bl, i) * vr[ii] : __shfl(wscl, i) * bf2f(kbuf[i][kcol]);
                float s = rhs - acc8[ii];
#pragma unroll
                for (int jj = 0; jj < 8; jj++)
                    if (jj < ii) s -= BMt[bi * 8 + jj][i] * Yreg[jj];
                Yreg[ii] = s;
                outb[ii] = f2bf(s);
            }
            *(uint4*)&YT[col][bi * 8] = *(uint4*)outb;
#pragma unroll
            for (int ii = 0; ii < 8; ii++) {
                if (isV)
                    Tv_g[cb + (bi * 8 + ii) * 128 + kcol] = outb[ii];
                else
                    Tw_g[cb + (bi * 8 + ii) * 128 + kcol] = outb[ii];
            }
        }
    }
    __syncthreads();

    // Gram_qk -> L (bf16, stride 72, overlays kbuf)
    {
        f32x4 qk_[4];
#pragma unroll
        for (int nj = 0; nj < 4; nj++) qk_[nj] = (f32x4){0.f, 0.f, 0.f, 0.f};
#pragma unroll
        for (int kk = 0; kk < 4; kk++) {
            bf16x8 a = *(const bf16x8*)&qn[(tokbase + w * 16 + l15) * 2048 + hk * 128 + kk * 32 +
                                           quad * 8];
#pragma unroll
            for (int nj = 0; nj < 4; nj++) {
                bf16x8 bb = *(const bf16x8*)&kbuf[nj * 16 + l15][kk * 32 + quad * 8];
                qk_[nj] = MFMA16(a, bb, qk_[nj]);
            }
        }
        __syncthreads();  // all kbuf reads done before Lbf overwrite
#pragma unroll
        for (int nj = 0; nj < 4; nj++)
#pragma unroll
            for (int r = 0; r < 4; r++) {
                int t = w * 16 + quad * 4 + r;
                int rr = nj * 16 + l15;
                float cgt = __shfl(cgl, t), cgr = __shfl(cgl, rr);
                float val = (rr <= t) ? qk_[nj][r] * __expf(cgt - cgr) : 0.f;
                Lbf[t * 72 + rr] = f2bf(val);
            }
    }
    __syncthreads();

    // O_loc = L*Tv -> obuf ; Q2 = Qtilde - L*Tw   (A=Lbf b128, B=YT b128)
#pragma unroll 1
    for (int half = 0; half < 2; half++) {
        f32x4 oa[8];
#pragma unroll
        for (int nj = 0; nj < 8; nj++) oa[nj] = (f32x4){0.f, 0.f, 0.f, 0.f};
#pragma unroll
        for (int kk = 0; kk < 2; kk++) {
            bf16x8 a = *(const bf16x8*)&Lbf[(w * 16 + l15) * 72 + kk * 32 + quad * 8];
#pragma unroll
            for (int nj = 0; nj < 8; nj++) {
                bf16x8 bb = *(const bf16x8*)&YT[half * 128 + nj * 16 + l15][kk * 32 + quad * 8];
                oa[nj] = MFMA16(a, bb, oa[nj]);
            }
        }
        if (half == 0) {
#pragma unroll
            for (int nj = 0; nj < 8; nj++)
#pragma unroll
                for (int r = 0; r < 4; r++) {
                    int t = w * 16 + quad * 4 + r;
                    int vcol = nj * 16 + l15;
                    obuf[(tokbase + t) * 4096 + h * 128 + vcol] = f2bf(oa[nj][r]);
                }
        } else {
#pragma unroll
            for (int nj = 0; nj < 8; nj++)
#pragma unroll
                for (int r = 0; r < 4; r++) {
                    int t = w * 16 + quad * 4 + r;
                    int kcol = nj * 16 + l15;
                    float qsc = __shfl(eCgl, t);
                    float qv = bf2f(qn[(tokbase + t) * 2048 + hk * 128 + kcol]);
                    Q2_g[cb + t * 128 + kcol] = f2bf(qsc * qv - oa[nj][r]);
                }
        }
    }
}

// ---------------- phase B: sequential chunk recurrence, software-pipelined ----------------
__global__ __launch_bounds__(256) void phaseB(const u16* __restrict__ kn,
                                              const float* __restrict__ g,
                                              const u16* __restrict__ Tv_g,
                                              const u16* __restrict__ Tw_g,
                                              const u16* __restrict__ Q2_g,
                                              u16* __restrict__ obuf) {
    __shared__ __align__(16) float Sf[128][32];
    __shared__ __align__(16) u16 SbfT[32][136];
    __shared__ __align__(16) u16 KhT[128][72];
    __shared__ __align__(16) u16 Ut[32][72];

    int bid = blockIdx.x;
    int vq = bid & 3, h = (bid >> 2) & 31, b = bid >> 7;
    int hk = h >> 1;
    int tid = threadIdx.x, lane = tid & 63, w = tid >> 6;
    int quad = lane >> 4, l15 = lane & 15;

    for (int p = tid; p < 128 * 32; p += 256) ((float*)Sf)[p] = 0.f;
    for (int p = tid; p < 32 * 136; p += 256) ((u16*)SbfT)[p] = 0;
    __syncthreads();

    float gl_pf;
    uint4 kreg[4];
    bf16x8 aTw[4], aQ2[4];
    u16 tvv_pf[2][4], oold[2][4];

#define PB_PREFETCH(cc)                                                                      \
    {                                                                                        \
        long tb_ = (long)b * T_SEQ + (cc) * 64;                                              \
        long cb_ = ((long)((b * 32 + h) * 32) + (cc)) * 8192;                                \
        gl_pf = g[(tb_ + lane) * 32 + h];                                                    \
        const u16* kp_ = &kn[(tb_ + lane) * 2048 + hk * 128 + w * 32];                       \
        kreg[0] = *(const uint4*)&kp_[0];                                                    \
        kreg[1] = *(const uint4*)&kp_[8];                                                    \
        kreg[2] = *(const uint4*)&kp_[16];                                                   \
        kreg[3] = *(const uint4*)&kp_[24];                                                   \
        _Pragma("unroll") for (int kk = 0; kk < 4; kk++) {                                   \
            aTw[kk] = *(const bf16x8*)&Tw_g[cb_ + (w * 16 + l15) * 128 + kk * 32 + quad * 8]; \
            aQ2[kk] = *(const bf16x8*)&Q2_g[cb_ + (w * 16 + l15) * 128 + kk * 32 + quad * 8]; \
        }                                                                                    \
        _Pragma("unroll") for (int nj = 0; nj < 2; nj++) _Pragma("unroll")                   \
            for (int r = 0; r < 4; r++) {                                                    \
            int i_ = w * 16 + quad * 4 + r;                                                  \
            int vg_ = vq * 32 + nj * 16 + l15;                                               \
            tvv_pf[nj][r] = Tv_g[cb_ + (long)i_ * 128 + vg_];                                \
            oold[nj][r] = obuf[(tb_ + i_) * 4096 + h * 128 + vg_];                           \
        }                                                                                    \
    }

    PB_PREFETCH(0);

    for (int c = 0; c < 32; ++c) {
        long tokbase = (long)b * T_SEQ + c * 64;
        float cgl = gl_pf;
#pragma unroll
        for (int d = 1; d < 64; d <<= 1) {
            float y = __shfl_up(cgl, d);
            if (lane >= d) cgl += y;
        }
        float cgC = __shfl(cgl, 63);
        float A_C = __expf(cgC);
        float kscl = __expf(cgC - cgl);

        {
            const u16* kk16 = (const u16*)kreg;
#pragma unroll
            for (int j = 0; j < 32; j++) KhT[w * 32 + j][lane] = f2bf(bf2f(kk16[j]) * kscl);
        }

        f32x4 y1[2], oo[2];
#pragma unroll
        for (int nj = 0; nj < 2; nj++) {
            y1[nj] = (f32x4){0.f, 0.f, 0.f, 0.f};
            oo[nj] = (f32x4){0.f, 0.f, 0.f, 0.f};
        }
#pragma unroll
        for (int kk = 0; kk < 4; kk++) {
#pragma unroll
            for (int nj = 0; nj < 2; nj++) {
                bf16x8 bb = *(const bf16x8*)&SbfT[nj * 16 + l15][kk * 32 + quad * 8];
                y1[nj] = MFMA16(aTw[kk], bb, y1[nj]);
                oo[nj] = MFMA16(aQ2[kk], bb, oo[nj]);
            }
        }
#pragma unroll
        for (int nj = 0; nj < 2; nj++)
#pragma unroll
            for (int r = 0; r < 4; r++) {
                int i = w * 16 + quad * 4 + r;
                int vl = nj * 16 + l15;
                int vg = vq * 32 + vl;
                Ut[vl][i] = f2bf(bf2f(tvv_pf[nj][r]) - y1[nj][r]);
                obuf[(tokbase + i) * 4096 + h * 128 + vg] = f2bf(bf2f(oold[nj][r]) + oo[nj][r]);
            }
        __syncthreads();

        if (c + 1 < 32) PB_PREFETCH(c + 1);

#pragma unroll
        for (int mm = 0; mm < 2; mm++) {
            int mi = 2 * w + mm;
#pragma unroll
            for (int nj = 0; nj < 2; nj++) {
                f32x4 sacc;
#pragma unroll
                for (int r = 0; r < 4; r++)
                    sacc[r] = A_C * Sf[mi * 16 + quad * 4 + r][nj * 16 + l15];
#pragma unroll
                for (int kk = 0; kk < 2; kk++) {
                    bf16x8 a = *(const bf16x8*)&KhT[mi * 16 + l15][kk * 32 + quad * 8];
                    bf16x8 bb = *(const bf16x8*)&Ut[nj * 16 + l15][kk * 32 + quad * 8];
                    sacc = MFMA16(a, bb, sacc);
                }
#pragma unroll
                for (int r = 0; r < 4; r++) {
                    int kd = mi * 16 + quad * 4 + r, vl = nj * 16 + l15;
                    Sf[kd][vl] = sacc[r];
                    SbfT[vl][kd] = f2bf(sacc[r]);
                }
            }
        }
        __syncthreads();
    }
#undef PB_PREFETCH
}

// ---------------- gated RMSNorm ----------------
__global__ __launch_bounds__(256) void gated_norm(const u16* __restrict__ obuf,
                                                  const u16* __restrict__ zbuf,
                                                  const float* __restrict__ norm_w,
                                                  u16* __restrict__ xn) {
    int tok = blockIdx.x, tid = threadIdx.x;
    long obase = (long)tok * 4096 + tid * 16;
    u16 ob[16], zb[16];
    *(uint4*)(ob + 0) = *(const uint4*)&obuf[obase];
    *(uint4*)(ob + 8) = *(const uint4*)&obuf[obase + 8];
    *(uint4*)(zb + 0) = *(const uint4*)&zbuf[obase];
    *(uint4*)(zb + 8) = *(const uint4*)&zbuf[obase + 8];
    float x[16];
    float ss = 0.f;
#pragma unroll
    for (int i = 0; i < 16; i++) {
        float ov = bf2f(ob[i]);
        float zv = bf2f(zb[i]);
        float xv = ov * (zv / (1.f + expf(-zv)));
        x[i] = xv;
        ss += xv * xv;
    }
    ss += __shfl_xor(ss, 4, 8);
    ss += __shfl_xor(ss, 2, 8);
    ss += __shfl_xor(ss, 1, 8);
    float scale = rsqrtf(ss * (1.f / 128.f) + 1e-6f);
    int cbase = (tid * 16) & 127;
#pragma unroll
    for (int i = 0; i < 16; i++)
        xn[(long)tok * 4096 + tid * 16 + i] = f2bf(x[i] * scale * (1.f + norm_w[cbase + i]));
}

// ---------------- launch ----------------
extern "C" void kernel_launch(void* const* d_in, const int* in_sizes, int n_in, void* d_out,
                              int out_size, void* d_ws, size_t ws_size, hipStream_t stream) {
    const float* hidden = (const float*)d_in[0];
    const float* W_qkvz = (const float*)d_in[1];
    const float* W_ba = (const float*)d_in[2];
    const float* conv_w = (const float*)d_in[3];
    const float* A_log = (const float*)d_in[4];
    const float* dt_bias = (const float*)d_in[5];
    const float* norm_w = (const float*)d_in[6];
    const float* W_out = (const float*)d_in[7];
    float* out = (float*)d_out;

    char* ws = (char*)d_ws;
    u16* wqT = (u16*)(ws + 0);
    u16* qn = (u16*)(ws + 0);
    u16* vc = (u16*)(ws + 16777216L);
    u16* hidbf = (u16*)(ws + 50331648L);
    u16* kn = (u16*)(ws + 50331648L);
    u16* woT = (u16*)(ws + 67108864L);
    u16* qkv_raw = (u16*)(ws + 83886080L);
    u16* Tv = (u16*)(ws + 83886080L);
    u16* Tw = (u16*)(ws + 117440512L);
    u16* xn = (u16*)(ws + 83886080L);
    u16* WbaT = (u16*)(ws + 150994944L);
    u16* zbuf = (u16*)(ws + 150994944L);
    u16* Q2 = (u16*)(ws + 184549376L);
    float* g = (float*)(ws + 218103808L);
    float* beta = (float*)(ws + 218628096L);
    u16* obuf = vc;

    cast_f32_bf16<<<8192, 256, 0, stream>>>(hidden, hidbf, 8388608L);
    transpose_cast<<<dim3(384, 64), 256, 0, stream>>>(W_qkvz, wqT, 2048, 12288);
    transpose_cast<<<dim3(64, 128), 256, 0, stream>>>(W_out, woT, 4096, 2048);
    transpose_cast<<<dim3(2, 64), 256, 0, stream>>>(W_ba, WbaT, 2048, 64);
    ba_gemm<<<128, 256, 0, stream>>>(hidbf, WbaT, A_log, dt_bias, g, beta);
    gemm_bt<2><<<dim3(32, 96), 256, 0, stream>>>(hidbf, wqT, qkv_raw, zbuf, 4096, 12288, 2048,
                                                 2048, 2048, 0);
    conv_gate<<<4096, 256, 0, stream>>>(qkv_raw, conv_w, qn, kn, vc);
    phaseA<<<2048, 256, 0, stream>>>(qn, kn, vc, g, beta, Tv, Tw, Q2, obuf);
    phaseB<<<256, 256, 0, stream>>>(kn, g, Tv, Tw, Q2, obuf);
    gated_norm<<<4096, 256, 0, stream>>>(obuf, zbuf, norm_w, xn);
    gemm_bt<0><<<dim3(32, 16), 256, 0, stream>>>(xn, woT, out, nullptr, 4096, 2048, 4096, 4096,
                                                 4096, 2048);
}

// Round 6
// 981.654 us; speedup vs baseline: 1.1099x; 1.1099x over previous
//
#include <hip/hip_runtime.h>

typedef unsigned short u16;
typedef unsigned int u32;

typedef short bf16x8 __attribute__((ext_vector_type(8)));
typedef float f32x4 __attribute__((ext_vector_type(4)));
typedef float f32x16 __attribute__((ext_vector_type(16)));

#define T_SEQ 2048
#define MFMA16(a, b, c) __builtin_amdgcn_mfma_f32_16x16x32_bf16(a, b, c, 0, 0, 0)
#define MFMA32(a, b, c) __builtin_amdgcn_mfma_f32_32x32x16_bf16(a, b, c, 0, 0, 0)

__device__ __forceinline__ u16 f2bf(float f) {
    u32 u = __float_as_uint(f);
    u += 0x7fffu + ((u >> 16) & 1u);
    return (u16)(u >> 16);
}
__device__ __forceinline__ float bf2f(u16 s) {
    return __uint_as_float(((u32)s) << 16);
}
__device__ __forceinline__ void g2lds16(const u16* gp, u16* lp) {
    __builtin_amdgcn_global_load_lds((const __attribute__((address_space(1))) void*)gp,
                                     (__attribute__((address_space(3))) void*)lp, 16, 0, 0);
}

// ---------------- cast fp32 -> bf16 ----------------
__global__ __launch_bounds__(256) void cast_f32_bf16(const float* __restrict__ in,
                                                     u16* __restrict__ out, long n) {
    long i = ((long)blockIdx.x * 256 + threadIdx.x) * 4;
    if (i + 3 < n) {
        float4 v = *(const float4*)&in[i];
        out[i + 0] = f2bf(v.x);
        out[i + 1] = f2bf(v.y);
        out[i + 2] = f2bf(v.z);
        out[i + 3] = f2bf(v.w);
    }
}

// ---------------- transpose + cast: [R,C] f32 -> [C,R] bf16 ----------------
__global__ __launch_bounds__(256) void transpose_cast(const float* __restrict__ in,
                                                      u16* __restrict__ out, int R, int C) {
    __shared__ float tile[32][33];
    int c0 = blockIdx.x * 32, r0 = blockIdx.y * 32;
    int tx = threadIdx.x & 31, ty = threadIdx.x >> 5;
#pragma unroll
    for (int rr = 0; rr < 32; rr += 8)
        tile[ty + rr][tx] = in[(long)(r0 + ty + rr) * C + c0 + tx];
    __syncthreads();
#pragma unroll
    for (int rr = 0; rr < 32; rr += 8)
        out[(long)(c0 + ty + rr) * R + r0 + tx] = f2bf(tile[tx][ty + rr]);
}

// ---------------- GEMM: C[M,N] = A[M,K] * BT[N,K], 32x32x16 MFMA, XOR-swizzled LDS --------
// MODE 0: f32 out ; MODE 2: split bf16 qkv(cols<8192, ld 8192)/z(ld 4096)
template <int MODE>
__global__ __launch_bounds__(256) void gemm_bt(const u16* __restrict__ A,
                                               const u16* __restrict__ B, void* __restrict__ C,
                                               void* __restrict__ C2, int M, int N, int K, int lda,
                                               int ldb, int ldc) {
    __shared__ __align__(16) u16 As[128 * 32];
    __shared__ __align__(16) u16 Bs[128 * 32];
    int m0 = blockIdx.x * 128, n0 = blockIdx.y * 128;
    int tid = threadIdx.x;
    int lane = tid & 63, w = tid >> 6;
    int wr = w >> 1, wc = w & 1;
    int l31 = lane & 31, hf = lane >> 5;
    int swz = (l31 >> 1) & 3;  // fragment-read cell swizzle

    f32x16 acc[2][2];
#pragma unroll
    for (int mi = 0; mi < 2; mi++)
#pragma unroll
        for (int nj = 0; nj < 2; nj++)
#pragma unroll
            for (int r = 0; r < 16; r++) acc[mi][nj][r] = 0.f;

    // staging: LDS cell (row, tid&3) holds global column-group (tid&3)^((srow>>1)&3)
    int srow = tid >> 2;
    int sc8 = (((tid & 3) ^ ((srow >> 1) & 3))) * 8;
    const u16* Ag = &A[(long)(m0 + srow) * lda + sc8];
    const u16* Bg = &B[(long)(n0 + srow) * ldb + sc8];

    for (int k0 = 0; k0 < K; k0 += 32) {
        g2lds16(Ag + k0, &As[tid * 8]);
        g2lds16(Ag + (long)64 * lda + k0, &As[(256 + tid) * 8]);
        g2lds16(Bg + k0, &Bs[tid * 8]);
        g2lds16(Bg + (long)64 * ldb + k0, &Bs[(256 + tid) * 8]);
        __syncthreads();
        bf16x8 af[2][2], bfr[2][2];
#pragma unroll
        for (int mi = 0; mi < 2; mi++)
#pragma unroll
            for (int ks = 0; ks < 2; ks++) {
                int cellA = ((ks * 2 + hf) ^ swz) * 8;
                af[mi][ks] = *(const bf16x8*)&As[(wr * 64 + mi * 32 + l31) * 32 + cellA];
                bfr[mi][ks] = *(const bf16x8*)&Bs[(wc * 64 + mi * 32 + l31) * 32 + cellA];
            }
#pragma unroll
        for (int ks = 0; ks < 2; ks++)
#pragma unroll
            for (int mi = 0; mi < 2; mi++)
#pragma unroll
                for (int nj = 0; nj < 2; nj++)
                    acc[mi][nj] = MFMA32(af[mi][ks], bfr[nj][ks], acc[mi][nj]);
        __syncthreads();
    }

    if (MODE == 0) {
#pragma unroll
        for (int mi = 0; mi < 2; mi++)
#pragma unroll
            for (int nj = 0; nj < 2; nj++)
#pragma unroll
                for (int r = 0; r < 16; r++) {
                    int row = m0 + wr * 64 + mi * 32 + (r >> 2) * 8 + hf * 4 + (r & 3);
                    int col = n0 + wc * 64 + nj * 32 + l31;
                    ((float*)C)[(long)row * ldc + col] = acc[mi][nj][r];
                }
    } else {
        u16* dst;
        long dldc;
        int ncol0;
        if (MODE == 2 && n0 >= 8192) {
            dst = (u16*)C2;
            dldc = 4096;
            ncol0 = n0 - 8192;
        } else {
            dst = (u16*)C;
            dldc = (MODE == 2) ? 8192 : ldc;
            ncol0 = n0;
        }
#pragma unroll 1
        for (int half_e = 0; half_e < 2; half_e++) {
            __syncthreads();
            if (wc == half_e) {
#pragma unroll
                for (int mi = 0; mi < 2; mi++)
#pragma unroll
                    for (int nj = 0; nj < 2; nj++)
#pragma unroll
                        for (int r = 0; r < 16; r++) {
                            int row = wr * 64 + mi * 32 + (r >> 2) * 8 + hf * 4 + (r & 3);
                            int col = nj * 32 + l31;
                            u16* base = (row < 64) ? As : Bs;
                            base[(row & 63) * 64 + col] = f2bf(acc[mi][nj][r]);
                        }
            }
            __syncthreads();
#pragma unroll
            for (int rr = 0; rr < 4; rr++) {
                int row = rr * 32 + (tid >> 3), seg = tid & 7;
                u16* base = (row < 64) ? As : Bs;
                *(uint4*)&dst[(long)(m0 + row) * dldc + ncol0 + half_e * 64 + seg * 8] =
                    *(uint4*)&base[(row & 63) * 64 + seg * 8];
            }
        }
    }
}

// ---------------- ba = hidden @ W_ba -> g, beta (MFMA, padded LDS) ----------------
__global__ __launch_bounds__(256) void ba_gemm(const u16* __restrict__ hid,
                                               const u16* __restrict__ WbaT,
                                               const float* __restrict__ A_log,
                                               const float* __restrict__ dt_bias,
                                               float* __restrict__ g, float* __restrict__ beta) {
    __shared__ __align__(16) u16 As2[32 * 40];
    __shared__ __align__(16) u16 Bs2[64 * 40];
    int m0 = blockIdx.x * 32;
    int tid = threadIdx.x, lane = tid & 63, w = tid >> 6;
    int quad = lane >> 4, l15 = lane & 15;
    int trow = w & 1;
    int ctile = (w >> 1) * 2;
    f32x4 acc[2];
    acc[0] = (f32x4){0.f, 0.f, 0.f, 0.f};
    acc[1] = (f32x4){0.f, 0.f, 0.f, 0.f};
    int srow = tid >> 2, sc8 = (tid & 3) * 8;
    for (int k0 = 0; k0 < 2048; k0 += 32) {
        if (tid < 128)
            *(uint4*)&As2[srow * 40 + sc8] =
                *(const uint4*)&hid[(long)(m0 + srow) * 2048 + k0 + sc8];
        *(uint4*)&Bs2[srow * 40 + sc8] = *(const uint4*)&WbaT[(long)srow * 2048 + k0 + sc8];
        __syncthreads();
        bf16x8 a = *(const bf16x8*)&As2[(trow * 16 + l15) * 40 + quad * 8];
#pragma unroll
        for (int j = 0; j < 2; j++) {
            bf16x8 b = *(const bf16x8*)&Bs2[((ctile + j) * 16 + l15) * 40 + quad * 8];
            acc[j] = MFMA16(a, b, acc[j]);
        }
        __syncthreads();
    }
#pragma unroll
    for (int j = 0; j < 2; j++)
#pragma unroll
        for (int r = 0; r < 4; r++) {
            int tok = m0 + trow * 16 + quad * 4 + r;
            int col = (ctile + j) * 16 + l15;
            float tot = acc[j][r];
            if (col < 32) {
                beta[(long)tok * 32 + col] = 1.f / (1.f + expf(-tot));
            } else {
                int h = col - 32;
                float x = tot + dt_bias[h];
                float sp = (x > 20.f) ? x : log1pf(expf(x));
                g[(long)tok * 32 + h] = -expf(A_log[h]) * sp;
            }
        }
}

// ---------------- causal conv + SiLU + l2norm + split (coalesced, LDS) ----------------
__global__ __launch_bounds__(256) void conv_gate(const u16* __restrict__ qkv,
                                                 const float* __restrict__ conv_w,
                                                 u16* __restrict__ qn, u16* __restrict__ kn,
                                                 u16* __restrict__ vc) {
    int tok = blockIdx.x, tid = threadIdx.x;
    int tloc = tok & (T_SEQ - 1);
    __shared__ float mixed[8192];
    __shared__ float sh_norm[32];
    uint4 zero4;
    zero4.x = zero4.y = zero4.z = zero4.w = 0u;
#pragma unroll
    for (int i = 0; i < 4; i++) {
        int c = (i * 256 + tid) * 8;
        long base = (long)tok * 8192 + c;
        uint4 x3 = *(const uint4*)&qkv[base];
        uint4 x2 = (tloc >= 1) ? *(const uint4*)&qkv[base - 8192] : zero4;
        uint4 x1 = (tloc >= 2) ? *(const uint4*)&qkv[base - 16384] : zero4;
        uint4 x0 = (tloc >= 3) ? *(const uint4*)&qkv[base - 24576] : zero4;
        const u16* p0 = (const u16*)&x0;
        const u16* p1 = (const u16*)&x1;
        const u16* p2 = (const u16*)&x2;
        const u16* p3 = (const u16*)&x3;
#pragma unroll
        for (int e = 0; e < 8; e++) {
            float4 wv = *(const float4*)&conv_w[(long)(c + e) * 4];
            float a = bf2f(p0[e]) * wv.x + bf2f(p1[e]) * wv.y + bf2f(p2[e]) * wv.z +
                      bf2f(p3[e]) * wv.w;
            mixed[c + e] = a / (1.f + __expf(-a));
        }
    }
    __syncthreads();
    int grp = tid >> 3, sub = tid & 7;
    float ss = 0.f;
#pragma unroll
    for (int e = 0; e < 16; e++) {
        float v = mixed[grp * 128 + sub * 16 + e];
        ss += v * v;
    }
    ss += __shfl_xor(ss, 4, 8);
    ss += __shfl_xor(ss, 2, 8);
    ss += __shfl_xor(ss, 1, 8);
    if (sub == 0) sh_norm[grp] = rsqrtf(ss + 1e-6f);
    __syncthreads();
#pragma unroll
    for (int i = 0; i < 4; i++) {
        int c = (i * 256 + tid) * 8;
        float nf = (c < 2048) ? sh_norm[c >> 7] * 0.08838834764831845f
                              : ((c < 4096) ? sh_norm[c >> 7] : 1.f);
        u16 ob[8];
#pragma unroll
        for (int e = 0; e < 8; e++) ob[e] = f2bf(mixed[c + e] * nf);
        uint4 val = *(uint4*)ob;
        if (c < 2048)
            *(uint4*)&qn[(long)tok * 2048 + c] = val;
        else if (c < 4096)
            *(uint4*)&kn[(long)tok * 2048 + (c - 2048)] = val;
        else
            *(uint4*)&vc[(long)tok * 4096 + (c - 4096)] = val;
    }
}

// ---------------- phase A: per-chunk WY transform (padded LDS, YT transposed) ----------
__global__ __launch_bounds__(256) void phaseA(const u16* __restrict__ qn,
                                              const u16* __restrict__ kn,
                                              const u16* __restrict__ vc,
                                              const float* __restrict__ g,
                                              const float* __restrict__ beta,
                                              u16* __restrict__ Tv_g, u16* __restrict__ Tw_g,
                                              u16* __restrict__ Q2_g, u16* __restrict__ obuf) {
    __shared__ __align__(16) u16 kbuf[64][136];  // k tile (padded); later L at stride 72
    __shared__ __align__(16) float BMt[64][68];  // BMt[j][i] (padded)
    __shared__ __align__(16) u16 YT[256][72];    // Y^T: row=col(0..127 V / 128..255 W), col=token
    u16* Lbf = &kbuf[0][0];

    int bid = blockIdx.x;
    int c = bid & 31, h = (bid >> 5) & 31, b = bid >> 10;
    int hk = h >> 1;
    long tokbase = (long)b * T_SEQ + c * 64;
    long cb = (long)bid * 8192;
    int tid = threadIdx.x, lane = tid & 63, w = tid >> 6;
    int quad = lane >> 4, l15 = lane & 15;

    float gl = g[(tokbase + lane) * 32 + h];
    float bl = beta[(tokbase + lane) * 32 + h];
    float cgl = gl;
#pragma unroll
    for (int d = 1; d < 64; d <<= 1) {
        float y = __shfl_up(cgl, d);
        if (lane >= d) cgl += y;
    }
    float wscl = bl * __expf(cgl);
    float eCgl = __expf(cgl);

#pragma unroll
    for (int p = 0; p < 4; p++) {
        int u = p * 256 + tid;
        int row = u >> 4, col8 = (u & 15) * 8;
        *(uint4*)&kbuf[row][col8] = *(const uint4*)&kn[(tokbase + row) * 2048 + hk * 128 + col8];
    }
    __syncthreads();

    // Gram_kk -> BMt
    {
        f32x4 gk[4];
#pragma unroll
        for (int nj = 0; nj < 4; nj++) gk[nj] = (f32x4){0.f, 0.f, 0.f, 0.f};
#pragma unroll
        for (int kk = 0; kk < 4; kk++) {
            bf16x8 a = *(const bf16x8*)&kbuf[w * 16 + l15][kk * 32 + quad * 8];
#pragma unroll
            for (int nj = 0; nj < 4; nj++) {
                bf16x8 bb = *(const bf16x8*)&kbuf[nj * 16 + l15][kk * 32 + quad * 8];
                gk[nj] = MFMA16(a, bb, gk[nj]);
            }
        }
#pragma unroll
        for (int nj = 0; nj < 4; nj++)
#pragma unroll
            for (int r = 0; r < 4; r++) {
                int i = w * 16 + quad * 4 + r;
                int j = nj * 16 + l15;
                float cgi = __shfl(cgl, i), cgj = __shfl(cgl, j);
                float bi = __shfl(bl, i);
                BMt[j][i] = (j < i) ? bi * gk[nj][r] * __expf(cgi - cgj) : 0.f;
            }
    }
    __syncthreads();

    // blocked forward substitution: (I+BM) Y = B*[V | W] ; Y^T into YT
    {
        int col = tid;
        bool isV = col < 128;
        int kcol = col & 127;
        long vbase = tokbase * 4096 + h * 128 + kcol;
        float Yreg[8], acc8[8];
#pragma unroll 1
        for (int bi = 0; bi < 8; ++bi) {
            float vr[8];
            if (isV) {
#pragma unroll
                for (int ii = 0; ii < 8; ii++)
                    vr[ii] = bf2f(vc[vbase + (long)(bi * 8 + ii) * 4096]);
            }
#pragma unroll
            for (int ii = 0; ii < 8; ii++) acc8[ii] = 0.f;
            for (int j = 0; j < bi * 8; ++j) {
                float yv = bf2f(YT[col][j]);
                float4 m0 = *(const float4*)&BMt[j][bi * 8];
                float4 m1 = *(const float4*)&BMt[j][bi * 8 + 4];
                acc8[0] += m0.x * yv;
                acc8[1] += m0.y * yv;
                acc8[2] += m0.z * yv;
                acc8[3] += m0.w * yv;
                acc8[4] += m1.x * yv;
                acc8[5] += m1.y * yv;
                acc8[6] += m1.z * yv;
                acc8[7] += m1.w * yv;
            }
            u16 outb[8];
#pragma unroll
            for (int ii = 0; ii < 8; ii++) {
                int i = bi * 8 + ii;
                float rhs = isV ? __shfl(bl, i) * vr[ii] : __shfl(wscl, i) * bf2f(kbuf[i][kcol]);
                float s = rhs - acc8[ii];
#pragma unroll
                for (int jj = 0; jj < 8; jj++)
                    if (jj < ii) s -= BMt[bi * 8 + jj][i] * Yreg[jj];
                Yreg[ii] = s;
                outb[ii] = f2bf(s);
            }
            *(uint4*)&YT[col][bi * 8] = *(uint4*)outb;
#pragma unroll
            for (int ii = 0; ii < 8; ii++) {
                if (isV)
                    Tv_g[cb + (bi * 8 + ii) * 128 + kcol] = outb[ii];
                else
                    Tw_g[cb + (bi * 8 + ii) * 128 + kcol] = outb[ii];
            }
        }
    }
    __syncthreads();

    // Gram_qk -> L (bf16, stride 72, overlays kbuf)
    {
        f32x4 qk_[4];
#pragma unroll
        for (int nj = 0; nj < 4; nj++) qk_[nj] = (f32x4){0.f, 0.f, 0.f, 0.f};
#pragma unroll
        for (int kk = 0; kk < 4; kk++) {
            bf16x8 a = *(const bf16x8*)&qn[(tokbase + w * 16 + l15) * 2048 + hk * 128 + kk * 32 +
                                           quad * 8];
#pragma unroll
            for (int nj = 0; nj < 4; nj++) {
                bf16x8 bb = *(const bf16x8*)&kbuf[nj * 16 + l15][kk * 32 + quad * 8];
                qk_[nj] = MFMA16(a, bb, qk_[nj]);
            }
        }
        __syncthreads();  // all kbuf reads done before Lbf overwrite
#pragma unroll
        for (int nj = 0; nj < 4; nj++)
#pragma unroll
            for (int r = 0; r < 4; r++) {
                int t = w * 16 + quad * 4 + r;
                int rr = nj * 16 + l15;
                float cgt = __shfl(cgl, t), cgr = __shfl(cgl, rr);
                float val = (rr <= t) ? qk_[nj][r] * __expf(cgt - cgr) : 0.f;
                Lbf[t * 72 + rr] = f2bf(val);
            }
    }
    __syncthreads();

    // O_loc = L*Tv -> obuf ; Q2 = Qtilde - L*Tw   (A=Lbf b128, B=YT b128)
#pragma unroll 1
    for (int half = 0; half < 2; half++) {
        f32x4 oa[8];
#pragma unroll
        for (int nj = 0; nj < 8; nj++) oa[nj] = (f32x4){0.f, 0.f, 0.f, 0.f};
#pragma unroll
        for (int kk = 0; kk < 2; kk++) {
            bf16x8 a = *(const bf16x8*)&Lbf[(w * 16 + l15) * 72 + kk * 32 + quad * 8];
#pragma unroll
            for (int nj = 0; nj < 8; nj++) {
                bf16x8 bb = *(const bf16x8*)&YT[half * 128 + nj * 16 + l15][kk * 32 + quad * 8];
                oa[nj] = MFMA16(a, bb, oa[nj]);
            }
        }
        if (half == 0) {
#pragma unroll
            for (int nj = 0; nj < 8; nj++)
#pragma unroll
                for (int r = 0; r < 4; r++) {
                    int t = w * 16 + quad * 4 + r;
                    int vcol = nj * 16 + l15;
                    obuf[(tokbase + t) * 4096 + h * 128 + vcol] = f2bf(oa[nj][r]);
                }
        } else {
#pragma unroll
            for (int nj = 0; nj < 8; nj++)
#pragma unroll
                for (int r = 0; r < 4; r++) {
                    int t = w * 16 + quad * 4 + r;
                    int kcol = nj * 16 + l15;
                    float qsc = __shfl(eCgl, t);
                    float qv = bf2f(qn[(tokbase + t) * 2048 + hk * 128 + kcol]);
                    Q2_g[cb + t * 128 + kcol] = f2bf(qsc * qv - oa[nj][r]);
                }
        }
    }
}

// ---------------- phase B: sequential chunk recurrence, software-pipelined ----------------
__global__ __launch_bounds__(256) void phaseB(const u16* __restrict__ kn,
                                              const float* __restrict__ g,
                                              const u16* __restrict__ Tv_g,
                                              const u16* __restrict__ Tw_g,
                                              const u16* __restrict__ Q2_g,
                                              u16* __restrict__ obuf) {
    __shared__ __align__(16) float Sf[128][32];
    __shared__ __align__(16) u16 SbfT[32][136];
    __shared__ __align__(16) u16 KhT[128][72];
    __shared__ __align__(16) u16 Ut[32][72];

    int bid = blockIdx.x;
    int vq = bid & 3, h = (bid >> 2) & 31, b = bid >> 7;
    int hk = h >> 1;
    int tid = threadIdx.x, lane = tid & 63, w = tid >> 6;
    int quad = lane >> 4, l15 = lane & 15;

    for (int p = tid; p < 128 * 32; p += 256) ((float*)Sf)[p] = 0.f;
    for (int p = tid; p < 32 * 136; p += 256) ((u16*)SbfT)[p] = 0;
    __syncthreads();

    float gl_pf;
    uint4 kreg[4];
    bf16x8 aTw[4], aQ2[4];
    u16 tvv_pf[2][4], oold[2][4];

#define PB_PREFETCH(cc)                                                                      \
    {                                                                                        \
        long tb_ = (long)b * T_SEQ + (cc) * 64;                                              \
        long cb_ = ((long)((b * 32 + h) * 32) + (cc)) * 8192;                                \
        gl_pf = g[(tb_ + lane) * 32 + h];                                                    \
        const u16* kp_ = &kn[(tb_ + lane) * 2048 + hk * 128 + w * 32];                       \
        kreg[0] = *(const uint4*)&kp_[0];                                                    \
        kreg[1] = *(const uint4*)&kp_[8];                                                    \
        kreg[2] = *(const uint4*)&kp_[16];                                                   \
        kreg[3] = *(const uint4*)&kp_[24];                                                   \
        _Pragma("unroll") for (int kk = 0; kk < 4; kk++) {                                   \
            aTw[kk] = *(const bf16x8*)&Tw_g[cb_ + (w * 16 + l15) * 128 + kk * 32 + quad * 8]; \
            aQ2[kk] = *(const bf16x8*)&Q2_g[cb_ + (w * 16 + l15) * 128 + kk * 32 + quad * 8]; \
        }                                                                                    \
        _Pragma("unroll") for (int nj = 0; nj < 2; nj++) _Pragma("unroll")                   \
            for (int r = 0; r < 4; r++) {                                                    \
            int i_ = w * 16 + quad * 4 + r;                                                  \
            int vg_ = vq * 32 + nj * 16 + l15;                                               \
            tvv_pf[nj][r] = Tv_g[cb_ + (long)i_ * 128 + vg_];                                \
            oold[nj][r] = obuf[(tb_ + i_) * 4096 + h * 128 + vg_];                           \
        }                                                                                    \
    }

    PB_PREFETCH(0);

    for (int c = 0; c < 32; ++c) {
        long tokbase = (long)b * T_SEQ + c * 64;
        float cgl = gl_pf;
#pragma unroll
        for (int d = 1; d < 64; d <<= 1) {
            float y = __shfl_up(cgl, d);
            if (lane >= d) cgl += y;
        }
        float cgC = __shfl(cgl, 63);
        float A_C = __expf(cgC);
        float kscl = __expf(cgC - cgl);

        {
            const u16* kk16 = (const u16*)kreg;
#pragma unroll
            for (int j = 0; j < 32; j++) KhT[w * 32 + j][lane] = f2bf(bf2f(kk16[j]) * kscl);
        }

        f32x4 y1[2], oo[2];
#pragma unroll
        for (int nj = 0; nj < 2; nj++) {
            y1[nj] = (f32x4){0.f, 0.f, 0.f, 0.f};
            oo[nj] = (f32x4){0.f, 0.f, 0.f, 0.f};
        }
#pragma unroll
        for (int kk = 0; kk < 4; kk++) {
#pragma unroll
            for (int nj = 0; nj < 2; nj++) {
                bf16x8 bb = *(const bf16x8*)&SbfT[nj * 16 + l15][kk * 32 + quad * 8];
                y1[nj] = MFMA16(aTw[kk], bb, y1[nj]);
                oo[nj] = MFMA16(aQ2[kk], bb, oo[nj]);
            }
        }
#pragma unroll
        for (int nj = 0; nj < 2; nj++)
#pragma unroll
            for (int r = 0; r < 4; r++) {
                int i = w * 16 + quad * 4 + r;
                int vl = nj * 16 + l15;
                int vg = vq * 32 + vl;
                Ut[vl][i] = f2bf(bf2f(tvv_pf[nj][r]) - y1[nj][r]);
                obuf[(tokbase + i) * 4096 + h * 128 + vg] = f2bf(bf2f(oold[nj][r]) + oo[nj][r]);
            }
        __syncthreads();

        if (c + 1 < 32) PB_PREFETCH(c + 1);

#pragma unroll
        for (int mm = 0; mm < 2; mm++) {
            int mi = 2 * w + mm;
#pragma unroll
            for (int nj = 0; nj < 2; nj++) {
                f32x4 sacc;
#pragma unroll
                for (int r = 0; r < 4; r++)
                    sacc[r] = A_C * Sf[mi * 16 + quad * 4 + r][nj * 16 + l15];
#pragma unroll
                for (int kk = 0; kk < 2; kk++) {
                    bf16x8 a = *(const bf16x8*)&KhT[mi * 16 + l15][kk * 32 + quad * 8];
                    bf16x8 bb = *(const bf16x8*)&Ut[nj * 16 + l15][kk * 32 + quad * 8];
                    sacc = MFMA16(a, bb, sacc);
                }
#pragma unroll
                for (int r = 0; r < 4; r++) {
                    int kd = mi * 16 + quad * 4 + r, vl = nj * 16 + l15;
                    Sf[kd][vl] = sacc[r];
                    SbfT[vl][kd] = f2bf(sacc[r]);
                }
            }
        }
        __syncthreads();
    }
#undef PB_PREFETCH
}

// ---------------- gated RMSNorm ----------------
__global__ __launch_bounds__(256) void gated_norm(const u16* __restrict__ obuf,
                                                  const u16* __restrict__ zbuf,
                                                  const float* __restrict__ norm_w,
                                                  u16* __restrict__ xn) {
    int tok = blockIdx.x, tid = threadIdx.x;
    long obase = (long)tok * 4096 + tid * 16;
    u16 ob[16], zb[16];
    *(uint4*)(ob + 0) = *(const uint4*)&obuf[obase];
    *(uint4*)(ob + 8) = *(const uint4*)&obuf[obase + 8];
    *(uint4*)(zb + 0) = *(const uint4*)&zbuf[obase];
    *(uint4*)(zb + 8) = *(const uint4*)&zbuf[obase + 8];
    float x[16];
    float ss = 0.f;
#pragma unroll
    for (int i = 0; i < 16; i++) {
        float ov = bf2f(ob[i]);
        float zv = bf2f(zb[i]);
        float xv = ov * (zv / (1.f + expf(-zv)));
        x[i] = xv;
        ss += xv * xv;
    }
    ss += __shfl_xor(ss, 4, 8);
    ss += __shfl_xor(ss, 2, 8);
    ss += __shfl_xor(ss, 1, 8);
    float scale = rsqrtf(ss * (1.f / 128.f) + 1e-6f);
    int cbase = (tid * 16) & 127;
#pragma unroll
    for (int i = 0; i < 16; i++)
        xn[(long)tok * 4096 + tid * 16 + i] = f2bf(x[i] * scale * (1.f + norm_w[cbase + i]));
}

// ---------------- launch ----------------
extern "C" void kernel_launch(void* const* d_in, const int* in_sizes, int n_in, void* d_out,
                              int out_size, void* d_ws, size_t ws_size, hipStream_t stream) {
    const float* hidden = (const float*)d_in[0];
    const float* W_qkvz = (const float*)d_in[1];
    const float* W_ba = (const float*)d_in[2];
    const float* conv_w = (const float*)d_in[3];
    const float* A_log = (const float*)d_in[4];
    const float* dt_bias = (const float*)d_in[5];
    const float* norm_w = (const float*)d_in[6];
    const float* W_out = (const float*)d_in[7];
    float* out = (float*)d_out;

    char* ws = (char*)d_ws;
    u16* wqT = (u16*)(ws + 0);
    u16* qn = (u16*)(ws + 0);
    u16* vc = (u16*)(ws + 16777216L);
    u16* hidbf = (u16*)(ws + 50331648L);
    u16* kn = (u16*)(ws + 50331648L);
    u16* woT = (u16*)(ws + 67108864L);
    u16* qkv_raw = (u16*)(ws + 83886080L);
    u16* Tv = (u16*)(ws + 83886080L);
    u16* Tw = (u16*)(ws + 117440512L);
    u16* xn = (u16*)(ws + 83886080L);
    u16* WbaT = (u16*)(ws + 150994944L);
    u16* zbuf = (u16*)(ws + 150994944L);
    u16* Q2 = (u16*)(ws + 184549376L);
    float* g = (float*)(ws + 218103808L);
    float* beta = (float*)(ws + 218628096L);
    u16* obuf = vc;

    cast_f32_bf16<<<8192, 256, 0, stream>>>(hidden, hidbf, 8388608L);
    transpose_cast<<<dim3(384, 64), 256, 0, stream>>>(W_qkvz, wqT, 2048, 12288);
    transpose_cast<<<dim3(64, 128), 256, 0, stream>>>(W_out, woT, 4096, 2048);
    transpose_cast<<<dim3(2, 64), 256, 0, stream>>>(W_ba, WbaT, 2048, 64);
    ba_gemm<<<128, 256, 0, stream>>>(hidbf, WbaT, A_log, dt_bias, g, beta);
    gemm_bt<2><<<dim3(32, 96), 256, 0, stream>>>(hidbf, wqT, qkv_raw, zbuf, 4096, 12288, 2048,
                                                 2048, 2048, 0);
    conv_gate<<<4096, 256, 0, stream>>>(qkv_raw, conv_w, qn, kn, vc);
    phaseA<<<2048, 256, 0, stream>>>(qn, kn, vc, g, beta, Tv, Tw, Q2, obuf);
    phaseB<<<256, 256, 0, stream>>>(kn, g, Tv, Tw, Q2, obuf);
    gated_norm<<<4096, 256, 0, stream>>>(obuf, zbuf, norm_w, xn);
    gemm_bt<0><<<dim3(32, 16), 256, 0, stream>>>(xn, woT, out, nullptr, 4096, 2048, 4096, 4096,
                                                 4096, 2048);
}

// Round 7
// 944.392 us; speedup vs baseline: 1.1537x; 1.0395x over previous
//
#include <hip/hip_runtime.h>

typedef unsigned short u16;
typedef unsigned int u32;

typedef short bf16x8 __attribute__((ext_vector_type(8)));
typedef float f32x4 __attribute__((ext_vector_type(4)));
typedef float f32x16 __attribute__((ext_vector_type(16)));

#define T_SEQ 2048
#define MFMA16(a, b, c) __builtin_amdgcn_mfma_f32_16x16x32_bf16(a, b, c, 0, 0, 0)
#define MFMA32(a, b, c) __builtin_amdgcn_mfma_f32_32x32x16_bf16(a, b, c, 0, 0, 0)

__device__ __forceinline__ u16 f2bf(float f) {
    u32 u = __float_as_uint(f);
    u += 0x7fffu + ((u >> 16) & 1u);
    return (u16)(u >> 16);
}
__device__ __forceinline__ float bf2f(u16 s) {
    return __uint_as_float(((u32)s) << 16);
}
__device__ __forceinline__ void g2lds16(const u16* gp, u16* lp) {
    __builtin_amdgcn_global_load_lds((const __attribute__((address_space(1))) void*)gp,
                                     (__attribute__((address_space(3))) void*)lp, 16, 0, 0);
}

// ---------------- cast fp32 -> bf16 ----------------
__global__ __launch_bounds__(256) void cast_f32_bf16(const float* __restrict__ in,
                                                     u16* __restrict__ out, long n) {
    long i = ((long)blockIdx.x * 256 + threadIdx.x) * 4;
    if (i + 3 < n) {
        float4 v = *(const float4*)&in[i];
        out[i + 0] = f2bf(v.x);
        out[i + 1] = f2bf(v.y);
        out[i + 2] = f2bf(v.z);
        out[i + 3] = f2bf(v.w);
    }
}

// ---------------- transpose + cast: [R,C] f32 -> [C,R] bf16 ----------------
__global__ __launch_bounds__(256) void transpose_cast(const float* __restrict__ in,
                                                      u16* __restrict__ out, int R, int C) {
    __shared__ float tile[32][33];
    int c0 = blockIdx.x * 32, r0 = blockIdx.y * 32;
    int tx = threadIdx.x & 31, ty = threadIdx.x >> 5;
#pragma unroll
    for (int rr = 0; rr < 32; rr += 8)
        tile[ty + rr][tx] = in[(long)(r0 + ty + rr) * C + c0 + tx];
    __syncthreads();
#pragma unroll
    for (int rr = 0; rr < 32; rr += 8)
        out[(long)(c0 + ty + rr) * R + r0 + tx] = f2bf(tile[tx][ty + rr]);
}

// ---------------- GEMM: C[M,N] = A[M,K] * BT[N,K], 32x32x16 MFMA, BK=64, XOR-swizzle ------
// LDS rows are 128B (64 u16) = 8 cells x 16B. Logical cell c of row r stored at c^(r&7).
// MODE 0: f32 out ; MODE 2: split bf16 qkv(cols<8192, ld 8192)/z(ld 4096)
template <int MODE>
__global__ __launch_bounds__(256) void gemm_bt(const u16* __restrict__ A,
                                               const u16* __restrict__ B, void* __restrict__ C,
                                               void* __restrict__ C2, int M, int N, int K, int lda,
                                               int ldb, int ldc) {
    __shared__ __align__(16) u16 As[128 * 64];
    __shared__ __align__(16) u16 Bs[128 * 64];
    int m0 = blockIdx.x * 128, n0 = blockIdx.y * 128;
    int tid = threadIdx.x;
    int lane = tid & 63, w = tid >> 6;
    int wr = w >> 1, wc = w & 1;
    int l31 = lane & 31, hf = lane >> 5;

    f32x16 acc[2][2];
#pragma unroll
    for (int mi = 0; mi < 2; mi++)
#pragma unroll
        for (int nj = 0; nj < 2; nj++)
#pragma unroll
            for (int r = 0; r < 16; r++) acc[mi][nj][r] = 0.f;

    // staging: thread covers row = p*32 + (tid>>3), physical cell (tid&7),
    // which holds global col-group (tid&7) ^ (row&7) = (tid&7) ^ ((tid>>3)&7).
    int srow = tid >> 3;
    int sc8 = ((tid & 7) ^ ((tid >> 3) & 7)) * 8;
    const u16* Ag = &A[(long)(m0 + srow) * lda + sc8];
    const u16* Bg = &B[(long)(n0 + srow) * ldb + sc8];

    for (int k0 = 0; k0 < K; k0 += 64) {
#pragma unroll
        for (int p = 0; p < 4; p++) {
            g2lds16(Ag + (long)p * 32 * lda + k0, &As[(p * 256 + tid) * 8]);
            g2lds16(Bg + (long)p * 32 * ldb + k0, &Bs[(p * 256 + tid) * 8]);
        }
        __syncthreads();
#pragma unroll
        for (int ks = 0; ks < 4; ks++) {
            int cell = ((ks * 2 + hf) ^ (l31 & 7)) * 8;
            bf16x8 a0 = *(const bf16x8*)&As[(wr * 64 + l31) * 64 + cell];
            bf16x8 a1 = *(const bf16x8*)&As[(wr * 64 + 32 + l31) * 64 + cell];
            bf16x8 b0 = *(const bf16x8*)&Bs[(wc * 64 + l31) * 64 + cell];
            bf16x8 b1 = *(const bf16x8*)&Bs[(wc * 64 + 32 + l31) * 64 + cell];
            acc[0][0] = MFMA32(a0, b0, acc[0][0]);
            acc[0][1] = MFMA32(a0, b1, acc[0][1]);
            acc[1][0] = MFMA32(a1, b0, acc[1][0]);
            acc[1][1] = MFMA32(a1, b1, acc[1][1]);
        }
        __syncthreads();
    }

    if (MODE == 0) {
#pragma unroll
        for (int mi = 0; mi < 2; mi++)
#pragma unroll
            for (int nj = 0; nj < 2; nj++)
#pragma unroll
                for (int r = 0; r < 16; r++) {
                    int row = m0 + wr * 64 + mi * 32 + (r >> 2) * 8 + hf * 4 + (r & 3);
                    int col = n0 + wc * 64 + nj * 32 + l31;
                    ((float*)C)[(long)row * ldc + col] = acc[mi][nj][r];
                }
    } else {
        u16* dst;
        long dldc;
        int ncol0;
        if (MODE == 2 && n0 >= 8192) {
            dst = (u16*)C2;
            dldc = 4096;
            ncol0 = n0 - 8192;
        } else {
            dst = (u16*)C;
            dldc = (MODE == 2) ? 8192 : ldc;
            ncol0 = n0;
        }
#pragma unroll 1
        for (int half_e = 0; half_e < 2; half_e++) {
            __syncthreads();
            if (wc == half_e) {
#pragma unroll
                for (int mi = 0; mi < 2; mi++)
#pragma unroll
                    for (int nj = 0; nj < 2; nj++)
#pragma unroll
                        for (int r = 0; r < 16; r++) {
                            int row = wr * 64 + mi * 32 + (r >> 2) * 8 + hf * 4 + (r & 3);
                            int col = nj * 32 + l31;
                            u16* base = (row < 64) ? As : Bs;
                            base[(row & 63) * 64 + col] = f2bf(acc[mi][nj][r]);
                        }
            }
            __syncthreads();
#pragma unroll
            for (int rr = 0; rr < 4; rr++) {
                int row = rr * 32 + (tid >> 3), seg = tid & 7;
                u16* base = (row < 64) ? As : Bs;
                *(uint4*)&dst[(long)(m0 + row) * dldc + ncol0 + half_e * 64 + seg * 8] =
                    *(uint4*)&base[(row & 63) * 64 + seg * 8];
            }
        }
    }
}

// ---------------- ba = hidden @ W_ba -> g, beta (MFMA, padded LDS) ----------------
__global__ __launch_bounds__(256) void ba_gemm(const u16* __restrict__ hid,
                                               const u16* __restrict__ WbaT,
                                               const float* __restrict__ A_log,
                                               const float* __restrict__ dt_bias,
                                               float* __restrict__ g, float* __restrict__ beta) {
    __shared__ __align__(16) u16 As2[32 * 40];
    __shared__ __align__(16) u16 Bs2[64 * 40];
    int m0 = blockIdx.x * 32;
    int tid = threadIdx.x, lane = tid & 63, w = tid >> 6;
    int quad = lane >> 4, l15 = lane & 15;
    int trow = w & 1;
    int ctile = (w >> 1) * 2;
    f32x4 acc[2];
    acc[0] = (f32x4){0.f, 0.f, 0.f, 0.f};
    acc[1] = (f32x4){0.f, 0.f, 0.f, 0.f};
    int srow = tid >> 2, sc8 = (tid & 3) * 8;
    for (int k0 = 0; k0 < 2048; k0 += 32) {
        if (tid < 128)
            *(uint4*)&As2[srow * 40 + sc8] =
                *(const uint4*)&hid[(long)(m0 + srow) * 2048 + k0 + sc8];
        *(uint4*)&Bs2[srow * 40 + sc8] = *(const uint4*)&WbaT[(long)srow * 2048 + k0 + sc8];
        __syncthreads();
        bf16x8 a = *(const bf16x8*)&As2[(trow * 16 + l15) * 40 + quad * 8];
#pragma unroll
        for (int j = 0; j < 2; j++) {
            bf16x8 b = *(const bf16x8*)&Bs2[((ctile + j) * 16 + l15) * 40 + quad * 8];
            acc[j] = MFMA16(a, b, acc[j]);
        }
        __syncthreads();
    }
#pragma unroll
    for (int j = 0; j < 2; j++)
#pragma unroll
        for (int r = 0; r < 4; r++) {
            int tok = m0 + trow * 16 + quad * 4 + r;
            int col = (ctile + j) * 16 + l15;
            float tot = acc[j][r];
            if (col < 32) {
                beta[(long)tok * 32 + col] = 1.f / (1.f + expf(-tot));
            } else {
                int h = col - 32;
                float x = tot + dt_bias[h];
                float sp = (x > 20.f) ? x : log1pf(expf(x));
                g[(long)tok * 32 + h] = -expf(A_log[h]) * sp;
            }
        }
}

// ---------------- causal conv + SiLU + l2norm + split (coalesced, LDS) ----------------
__global__ __launch_bounds__(256) void conv_gate(const u16* __restrict__ qkv,
                                                 const float* __restrict__ conv_w,
                                                 u16* __restrict__ qn, u16* __restrict__ kn,
                                                 u16* __restrict__ vc) {
    int tok = blockIdx.x, tid = threadIdx.x;
    int tloc = tok & (T_SEQ - 1);
    __shared__ float mixed[8192];
    __shared__ float sh_norm[32];
    uint4 zero4;
    zero4.x = zero4.y = zero4.z = zero4.w = 0u;
#pragma unroll
    for (int i = 0; i < 4; i++) {
        int c = (i * 256 + tid) * 8;
        long base = (long)tok * 8192 + c;
        uint4 x3 = *(const uint4*)&qkv[base];
        uint4 x2 = (tloc >= 1) ? *(const uint4*)&qkv[base - 8192] : zero4;
        uint4 x1 = (tloc >= 2) ? *(const uint4*)&qkv[base - 16384] : zero4;
        uint4 x0 = (tloc >= 3) ? *(const uint4*)&qkv[base - 24576] : zero4;
        const u16* p0 = (const u16*)&x0;
        const u16* p1 = (const u16*)&x1;
        const u16* p2 = (const u16*)&x2;
        const u16* p3 = (const u16*)&x3;
#pragma unroll
        for (int e = 0; e < 8; e++) {
            float4 wv = *(const float4*)&conv_w[(long)(c + e) * 4];
            float a = bf2f(p0[e]) * wv.x + bf2f(p1[e]) * wv.y + bf2f(p2[e]) * wv.z +
                      bf2f(p3[e]) * wv.w;
            mixed[c + e] = a / (1.f + __expf(-a));
        }
    }
    __syncthreads();
    int grp = tid >> 3, sub = tid & 7;
    float ss = 0.f;
#pragma unroll
    for (int e = 0; e < 16; e++) {
        float v = mixed[grp * 128 + sub * 16 + e];
        ss += v * v;
    }
    ss += __shfl_xor(ss, 4, 8);
    ss += __shfl_xor(ss, 2, 8);
    ss += __shfl_xor(ss, 1, 8);
    if (sub == 0) sh_norm[grp] = rsqrtf(ss + 1e-6f);
    __syncthreads();
#pragma unroll
    for (int i = 0; i < 4; i++) {
        int c = (i * 256 + tid) * 8;
        float nf = (c < 2048) ? sh_norm[c >> 7] * 0.08838834764831845f
                              : ((c < 4096) ? sh_norm[c >> 7] : 1.f);
        u16 ob[8];
#pragma unroll
        for (int e = 0; e < 8; e++) ob[e] = f2bf(mixed[c + e] * nf);
        uint4 val = *(uint4*)ob;
        if (c < 2048)
            *(uint4*)&qn[(long)tok * 2048 + c] = val;
        else if (c < 4096)
            *(uint4*)&kn[(long)tok * 2048 + (c - 2048)] = val;
        else
            *(uint4*)&vc[(long)tok * 4096 + (c - 4096)] = val;
    }
}

// ---------------- phase A: per-chunk WY transform (padded LDS, YT transposed) ----------
__global__ __launch_bounds__(256) void phaseA(const u16* __restrict__ qn,
                                              const u16* __restrict__ kn,
                                              const u16* __restrict__ vc,
                                              const float* __restrict__ g,
                                              const float* __restrict__ beta,
                                              u16* __restrict__ Tv_g, u16* __restrict__ Tw_g,
                                              u16* __restrict__ Q2_g, u16* __restrict__ obuf) {
    __shared__ __align__(16) u16 kbuf[64][136];  // k tile (padded); later L at stride 72
    __shared__ __align__(16) float BMt[64][68];  // BMt[j][i] (padded)
    __shared__ __align__(16) u16 YT[256][72];    // Y^T: row=col(0..127 V / 128..255 W), col=token
    u16* Lbf = &kbuf[0][0];

    int bid = blockIdx.x;
    int c = bid & 31, h = (bid >> 5) & 31, b = bid >> 10;
    int hk = h >> 1;
    long tokbase = (long)b * T_SEQ + c * 64;
    long cb = (long)bid * 8192;
    int tid = threadIdx.x, lane = tid & 63, w = tid >> 6;
    int quad = lane >> 4, l15 = lane & 15;

    float gl = g[(tokbase + lane) * 32 + h];
    float bl = beta[(tokbase + lane) * 32 + h];
    float cgl = gl;
#pragma unroll
    for (int d = 1; d < 64; d <<= 1) {
        float y = __shfl_up(cgl, d);
        if (lane >= d) cgl += y;
    }
    float wscl = bl * __expf(cgl);
    float eCgl = __expf(cgl);

#pragma unroll
    for (int p = 0; p < 4; p++) {
        int u = p * 256 + tid;
        int row = u >> 4, col8 = (u & 15) * 8;
        *(uint4*)&kbuf[row][col8] = *(const uint4*)&kn[(tokbase + row) * 2048 + hk * 128 + col8];
    }
    __syncthreads();

    // Gram_kk -> BMt
    {
        f32x4 gk[4];
#pragma unroll
        for (int nj = 0; nj < 4; nj++) gk[nj] = (f32x4){0.f, 0.f, 0.f, 0.f};
#pragma unroll
        for (int kk = 0; kk < 4; kk++) {
            bf16x8 a = *(const bf16x8*)&kbuf[w * 16 + l15][kk * 32 + quad * 8];
#pragma unroll
            for (int nj = 0; nj < 4; nj++) {
                bf16x8 bb = *(const bf16x8*)&kbuf[nj * 16 + l15][kk * 32 + quad * 8];
                gk[nj] = MFMA16(a, bb, gk[nj]);
            }
        }
#pragma unroll
        for (int nj = 0; nj < 4; nj++)
#pragma unroll
            for (int r = 0; r < 4; r++) {
                int i = w * 16 + quad * 4 + r;
                int j = nj * 16 + l15;
                float cgi = __shfl(cgl, i), cgj = __shfl(cgl, j);
                float bi = __shfl(bl, i);
                BMt[j][i] = (j < i) ? bi * gk[nj][r] * __expf(cgi - cgj) : 0.f;
            }
    }
    __syncthreads();

    // blocked forward substitution: (I+BM) Y = B*[V | W] ; Y^T into YT
    {
        int col = tid;
        bool isV = col < 128;
        int kcol = col & 127;
        long vbase = tokbase * 4096 + h * 128 + kcol;
        float Yreg[8], acc8[8];
#pragma unroll 1
        for (int bi = 0; bi < 8; ++bi) {
            float vr[8];
            if (isV) {
#pragma unroll
                for (int ii = 0; ii < 8; ii++)
                    vr[ii] = bf2f(vc[vbase + (long)(bi * 8 + ii) * 4096]);
            }
#pragma unroll
            for (int ii = 0; ii < 8; ii++) acc8[ii] = 0.f;
            for (int j = 0; j < bi * 8; ++j) {
                float yv = bf2f(YT[col][j]);
                float4 m0 = *(const float4*)&BMt[j][bi * 8];
                float4 m1 = *(const float4*)&BMt[j][bi * 8 + 4];
                acc8[0] += m0.x * yv;
                acc8[1] += m0.y * yv;
                acc8[2] += m0.z * yv;
                acc8[3] += m0.w * yv;
                acc8[4] += m1.x * yv;
                acc8[5] += m1.y * yv;
                acc8[6] += m1.z * yv;
                acc8[7] += m1.w * yv;
            }
            u16 outb[8];
#pragma unroll
            for (int ii = 0; ii < 8; ii++) {
                int i = bi * 8 + ii;
                float rhs = isV ? __shfl(bl, i) * vr[ii] : __shfl(wscl, i) * bf2f(kbuf[i][kcol]);
                float s = rhs - acc8[ii];
#pragma unroll
                for (int jj = 0; jj < 8; jj++)
                    if (jj < ii) s -= BMt[bi * 8 + jj][i] * Yreg[jj];
                Yreg[ii] = s;
                outb[ii] = f2bf(s);
            }
            *(uint4*)&YT[col][bi * 8] = *(uint4*)outb;
#pragma unroll
            for (int ii = 0; ii < 8; ii++) {
                if (isV)
                    Tv_g[cb + (bi * 8 + ii) * 128 + kcol] = outb[ii];
                else
                    Tw_g[cb + (bi * 8 + ii) * 128 + kcol] = outb[ii];
            }
        }
    }
    __syncthreads();

    // Gram_qk -> L (bf16, stride 72, overlays kbuf)
    {
        f32x4 qk_[4];
#pragma unroll
        for (int nj = 0; nj < 4; nj++) qk_[nj] = (f32x4){0.f, 0.f, 0.f, 0.f};
#pragma unroll
        for (int kk = 0; kk < 4; kk++) {
            bf16x8 a = *(const bf16x8*)&qn[(tokbase + w * 16 + l15) * 2048 + hk * 128 + kk * 32 +
                                           quad * 8];
#pragma unroll
            for (int nj = 0; nj < 4; nj++) {
                bf16x8 bb = *(const bf16x8*)&kbuf[nj * 16 + l15][kk * 32 + quad * 8];
                qk_[nj] = MFMA16(a, bb, qk_[nj]);
            }
        }
        __syncthreads();  // all kbuf reads done before Lbf overwrite
#pragma unroll
        for (int nj = 0; nj < 4; nj++)
#pragma unroll
            for (int r = 0; r < 4; r++) {
                int t = w * 16 + quad * 4 + r;
                int rr = nj * 16 + l15;
                float cgt = __shfl(cgl, t), cgr = __shfl(cgl, rr);
                float val = (rr <= t) ? qk_[nj][r] * __expf(cgt - cgr) : 0.f;
                Lbf[t * 72 + rr] = f2bf(val);
            }
    }
    __syncthreads();

    // O_loc = L*Tv -> obuf ; Q2 = Qtilde - L*Tw   (A=Lbf b128, B=YT b128)
#pragma unroll 1
    for (int half = 0; half < 2; half++) {
        f32x4 oa[8];
#pragma unroll
        for (int nj = 0; nj < 8; nj++) oa[nj] = (f32x4){0.f, 0.f, 0.f, 0.f};
#pragma unroll
        for (int kk = 0; kk < 2; kk++) {
            bf16x8 a = *(const bf16x8*)&Lbf[(w * 16 + l15) * 72 + kk * 32 + quad * 8];
#pragma unroll
            for (int nj = 0; nj < 8; nj++) {
                bf16x8 bb = *(const bf16x8*)&YT[half * 128 + nj * 16 + l15][kk * 32 + quad * 8];
                oa[nj] = MFMA16(a, bb, oa[nj]);
            }
        }
        if (half == 0) {
#pragma unroll
            for (int nj = 0; nj < 8; nj++)
#pragma unroll
                for (int r = 0; r < 4; r++) {
                    int t = w * 16 + quad * 4 + r;
                    int vcol = nj * 16 + l15;
                    obuf[(tokbase + t) * 4096 + h * 128 + vcol] = f2bf(oa[nj][r]);
                }
        } else {
#pragma unroll
            for (int nj = 0; nj < 8; nj++)
#pragma unroll
                for (int r = 0; r < 4; r++) {
                    int t = w * 16 + quad * 4 + r;
                    int kcol = nj * 16 + l15;
                    float qsc = __shfl(eCgl, t);
                    float qv = bf2f(qn[(tokbase + t) * 2048 + hk * 128 + kcol]);
                    Q2_g[cb + t * 128 + kcol] = f2bf(qsc * qv - oa[nj][r]);
                }
        }
    }
}

// ---------------- phase B: sequential chunk recurrence, software-pipelined ----------------
__global__ __launch_bounds__(256) void phaseB(const u16* __restrict__ kn,
                                              const float* __restrict__ g,
                                              const u16* __restrict__ Tv_g,
                                              const u16* __restrict__ Tw_g,
                                              const u16* __restrict__ Q2_g,
                                              u16* __restrict__ obuf) {
    __shared__ __align__(16) float Sf[128][32];
    __shared__ __align__(16) u16 SbfT[32][136];
    __shared__ __align__(16) u16 KhT[128][72];
    __shared__ __align__(16) u16 Ut[32][72];

    int bid = blockIdx.x;
    int vq = bid & 3, h = (bid >> 2) & 31, b = bid >> 7;
    int hk = h >> 1;
    int tid = threadIdx.x, lane = tid & 63, w = tid >> 6;
    int quad = lane >> 4, l15 = lane & 15;

    for (int p = tid; p < 128 * 32; p += 256) ((float*)Sf)[p] = 0.f;
    for (int p = tid; p < 32 * 136; p += 256) ((u16*)SbfT)[p] = 0;
    __syncthreads();

    float gl_pf;
    uint4 kreg[4];
    bf16x8 aTw[4], aQ2[4];
    u16 tvv_pf[2][4], oold[2][4];

#define PB_PREFETCH(cc)                                                                      \
    {                                                                                        \
        long tb_ = (long)b * T_SEQ + (cc) * 64;                                              \
        long cb_ = ((long)((b * 32 + h) * 32) + (cc)) * 8192;                                \
        gl_pf = g[(tb_ + lane) * 32 + h];                                                    \
        const u16* kp_ = &kn[(tb_ + lane) * 2048 + hk * 128 + w * 32];                       \
        kreg[0] = *(const uint4*)&kp_[0];                                                    \
        kreg[1] = *(const uint4*)&kp_[8];                                                    \
        kreg[2] = *(const uint4*)&kp_[16];                                                   \
        kreg[3] = *(const uint4*)&kp_[24];                                                   \
        _Pragma("unroll") for (int kk = 0; kk < 4; kk++) {                                   \
            aTw[kk] = *(const bf16x8*)&Tw_g[cb_ + (w * 16 + l15) * 128 + kk * 32 + quad * 8]; \
            aQ2[kk] = *(const bf16x8*)&Q2_g[cb_ + (w * 16 + l15) * 128 + kk * 32 + quad * 8]; \
        }                                                                                    \
        _Pragma("unroll") for (int nj = 0; nj < 2; nj++) _Pragma("unroll")                   \
            for (int r = 0; r < 4; r++) {                                                    \
            int i_ = w * 16 + quad * 4 + r;                                                  \
            int vg_ = vq * 32 + nj * 16 + l15;                                               \
            tvv_pf[nj][r] = Tv_g[cb_ + (long)i_ * 128 + vg_];                                \
            oold[nj][r] = obuf[(tb_ + i_) * 4096 + h * 128 + vg_];                           \
        }                                                                                    \
    }

    PB_PREFETCH(0);

    for (int c = 0; c < 32; ++c) {
        long tokbase = (long)b * T_SEQ + c * 64;
        float cgl = gl_pf;
#pragma unroll
        for (int d = 1; d < 64; d <<= 1) {
            float y = __shfl_up(cgl, d);
            if (lane >= d) cgl += y;
        }
        float cgC = __shfl(cgl, 63);
        float A_C = __expf(cgC);
        float kscl = __expf(cgC - cgl);

        {
            const u16* kk16 = (const u16*)kreg;
#pragma unroll
            for (int j = 0; j < 32; j++) KhT[w * 32 + j][lane] = f2bf(bf2f(kk16[j]) * kscl);
        }

        f32x4 y1[2], oo[2];
#pragma unroll
        for (int nj = 0; nj < 2; nj++) {
            y1[nj] = (f32x4){0.f, 0.f, 0.f, 0.f};
            oo[nj] = (f32x4){0.f, 0.f, 0.f, 0.f};
        }
#pragma unroll
        for (int kk = 0; kk < 4; kk++) {
#pragma unroll
            for (int nj = 0; nj < 2; nj++) {
                bf16x8 bb = *(const bf16x8*)&SbfT[nj * 16 + l15][kk * 32 + quad * 8];
                y1[nj] = MFMA16(aTw[kk], bb, y1[nj]);
                oo[nj] = MFMA16(aQ2[kk], bb, oo[nj]);
            }
        }
#pragma unroll
        for (int nj = 0; nj < 2; nj++)
#pragma unroll
            for (int r = 0; r < 4; r++) {
                int i = w * 16 + quad * 4 + r;
                int vl = nj * 16 + l15;
                int vg = vq * 32 + vl;
                Ut[vl][i] = f2bf(bf2f(tvv_pf[nj][r]) - y1[nj][r]);
                obuf[(tokbase + i) * 4096 + h * 128 + vg] = f2bf(bf2f(oold[nj][r]) + oo[nj][r]);
            }
        __syncthreads();

        if (c + 1 < 32) PB_PREFETCH(c + 1);

#pragma unroll
        for (int mm = 0; mm < 2; mm++) {
            int mi = 2 * w + mm;
#pragma unroll
            for (int nj = 0; nj < 2; nj++) {
                f32x4 sacc;
#pragma unroll
                for (int r = 0; r < 4; r++)
                    sacc[r] = A_C * Sf[mi * 16 + quad * 4 + r][nj * 16 + l15];
#pragma unroll
                for (int kk = 0; kk < 2; kk++) {
                    bf16x8 a = *(const bf16x8*)&KhT[mi * 16 + l15][kk * 32 + quad * 8];
                    bf16x8 bb = *(const bf16x8*)&Ut[nj * 16 + l15][kk * 32 + quad * 8];
                    sacc = MFMA16(a, bb, sacc);
                }
#pragma unroll
                for (int r = 0; r < 4; r++) {
                    int kd = mi * 16 + quad * 4 + r, vl = nj * 16 + l15;
                    Sf[kd][vl] = sacc[r];
                    SbfT[vl][kd] = f2bf(sacc[r]);
                }
            }
        }
        __syncthreads();
    }
#undef PB_PREFETCH
}

// ---------------- gated RMSNorm ----------------
__global__ __launch_bounds__(256) void gated_norm(const u16* __restrict__ obuf,
                                                  const u16* __restrict__ zbuf,
                                                  const float* __restrict__ norm_w,
                                                  u16* __restrict__ xn) {
    int tok = blockIdx.x, tid = threadIdx.x;
    long obase = (long)tok * 4096 + tid * 16;
    u16 ob[16], zb[16];
    *(uint4*)(ob + 0) = *(const uint4*)&obuf[obase];
    *(uint4*)(ob + 8) = *(const uint4*)&obuf[obase + 8];
    *(uint4*)(zb + 0) = *(const uint4*)&zbuf[obase];
    *(uint4*)(zb + 8) = *(const uint4*)&zbuf[obase + 8];
    float x[16];
    float ss = 0.f;
#pragma unroll
    for (int i = 0; i < 16; i++) {
        float ov = bf2f(ob[i]);
        float zv = bf2f(zb[i]);
        float xv = ov * (zv / (1.f + expf(-zv)));
        x[i] = xv;
        ss += xv * xv;
    }
    ss += __shfl_xor(ss, 4, 8);
    ss += __shfl_xor(ss, 2, 8);
    ss += __shfl_xor(ss, 1, 8);
    float scale = rsqrtf(ss * (1.f / 128.f) + 1e-6f);
    int cbase = (tid * 16) & 127;
#pragma unroll
    for (int i = 0; i < 16; i++)
        xn[(long)tok * 4096 + tid * 16 + i] = f2bf(x[i] * scale * (1.f + norm_w[cbase + i]));
}

// ---------------- launch ----------------
extern "C" void kernel_launch(void* const* d_in, const int* in_sizes, int n_in, void* d_out,
                              int out_size, void* d_ws, size_t ws_size, hipStream_t stream) {
    const float* hidden = (const float*)d_in[0];
    const float* W_qkvz = (const float*)d_in[1];
    const float* W_ba = (const float*)d_in[2];
    const float* conv_w = (const float*)d_in[3];
    const float* A_log = (const float*)d_in[4];
    const float* dt_bias = (const float*)d_in[5];
    const float* norm_w = (const float*)d_in[6];
    const float* W_out = (const float*)d_in[7];
    float* out = (float*)d_out;

    char* ws = (char*)d_ws;
    u16* wqT = (u16*)(ws + 0);
    u16* qn = (u16*)(ws + 0);
    u16* vc = (u16*)(ws + 16777216L);
    u16* hidbf = (u16*)(ws + 50331648L);
    u16* kn = (u16*)(ws + 50331648L);
    u16* woT = (u16*)(ws + 67108864L);
    u16* qkv_raw = (u16*)(ws + 83886080L);
    u16* Tv = (u16*)(ws + 83886080L);
    u16* Tw = (u16*)(ws + 117440512L);
    u16* xn = (u16*)(ws + 83886080L);
    u16* WbaT = (u16*)(ws + 150994944L);
    u16* zbuf = (u16*)(ws + 150994944L);
    u16* Q2 = (u16*)(ws + 184549376L);
    float* g = (float*)(ws + 218103808L);
    float* beta = (float*)(ws + 218628096L);
    u16* obuf = vc;

    cast_f32_bf16<<<8192, 256, 0, stream>>>(hidden, hidbf, 8388608L);
    transpose_cast<<<dim3(384, 64), 256, 0, stream>>>(W_qkvz, wqT, 2048, 12288);
    transpose_cast<<<dim3(64, 128), 256, 0, stream>>>(W_out, woT, 4096, 2048);
    transpose_cast<<<dim3(2, 64), 256, 0, stream>>>(W_ba, WbaT, 2048, 64);
    ba_gemm<<<128, 256, 0, stream>>>(hidbf, WbaT, A_log, dt_bias, g, beta);
    gemm_bt<2><<<dim3(32, 96), 256, 0, stream>>>(hidbf, wqT, qkv_raw, zbuf, 4096, 12288, 2048,
                                                 2048, 2048, 0);
    conv_gate<<<4096, 256, 0, stream>>>(qkv_raw, conv_w, qn, kn, vc);
    phaseA<<<2048, 256, 0, stream>>>(qn, kn, vc, g, beta, Tv, Tw, Q2, obuf);
    phaseB<<<256, 256, 0, stream>>>(kn, g, Tv, Tw, Q2, obuf);
    gated_norm<<<4096, 256, 0, stream>>>(obuf, zbuf, norm_w, xn);
    gemm_bt<0><<<dim3(32, 16), 256, 0, stream>>>(xn, woT, out, nullptr, 4096, 2048, 4096, 4096,
                                                 4096, 2048);
}